// Round 5
// baseline (1283.790 us; speedup 1.0000x reference)
//
#include <hip/hip_runtime.h>
#include <hip/hip_bf16.h>
#include <cstdint>

// Problem constants
#define B_ROWS 16384
#define DIN    8192
#define NE_    4      // codebook entries
#define NEXP   8
#define HDEC   256
#define NCOL   40     // 8 gate cols + 32 (e,lat) cols
#define ROWS_PB 16    // rows per block
#define CHUNK  256    // K per staged chunk
#define NCHUNK (DIN / CHUNK)   // 32
#define RPW 8         // rows per wave (row-group size)
#define CPW 5         // cols per wave

// ---------------- helpers ----------------
__device__ __forceinline__ float mishf(float x) {
    float sp = (x > 20.f) ? x : log1pf(expf(x));
    return x * tanhf(sp);
}
__device__ __forceinline__ double mishd(double x) {
    double sp = (x > 30.0) ? x : log1p(exp(x));
    return x * tanh(sp);
}
__device__ __forceinline__ void ln4d(const double* a, double* o) {
    double m  = (a[0] + a[1] + a[2] + a[3]) * 0.25;
    double d0 = a[0] - m, d1 = a[1] - m, d2 = a[2] - m, d3 = a[3] - m;
    double v  = (d0*d0 + d1*d1 + d2*d2 + d3*d3) * 0.25;
    double r  = 1.0 / sqrt(v + 1e-5);
    o[0] = d0*r; o[1] = d1*r; o[2] = d2*r; o[3] = d3*r;
}

// async global->LDS staging of one 40x256 f32 weight chunk (40960 B)
// float4 id f: j = f>>6, koff4 = f&63 ; lds linear float off = f*4
__device__ __forceinline__ void stage_w(const float* __restrict__ src,
                                        float* ldsbase, int t) {
    typedef const char __attribute__((address_space(1)))* gp_t;
    typedef char __attribute__((address_space(3)))* lp_t;
    int f0 = t, f1 = t + 1024;
    __builtin_amdgcn_global_load_lds(
        (gp_t)(const void*)(src + (size_t)(f0 >> 6) * DIN + ((f0 & 63) << 2)),
        (lp_t)(void*)(ldsbase + (f0 << 2)), 16, 0, 0);
    __builtin_amdgcn_global_load_lds(
        (gp_t)(const void*)(src + (size_t)(f1 >> 6) * DIN + ((f1 & 63) << 2)),
        (lp_t)(void*)(ldsbase + (f1 << 2)), 16, 0, 0);
    if (t < 512) {   // waves 0..7, fully uniform per wave
        int f2 = t + 2048;
        __builtin_amdgcn_global_load_lds(
            (gp_t)(const void*)(src + (size_t)(f2 >> 6) * DIN + ((f2 & 63) << 2)),
            (lp_t)(void*)(ldsbase + (f2 << 2)), 16, 0, 0);
    }
}

// ---------------------------------------------------------------------------
// Sentinel kernel: fires only if in_sizes don't match expectations.
// ---------------------------------------------------------------------------
__global__ __launch_bounds__(256) void sentinel_k(float* __restrict__ out, int n, float v) {
    int i = blockIdx.x * 256 + threadIdx.x;
    if (i < n) out[i] = v;
}

// ---------------------------------------------------------------------------
// Kernel 1: pack TRANSPOSED w40T[j][k]
// ---------------------------------------------------------------------------
__global__ __launch_bounds__(256) void prep_w40t(const float* __restrict__ gw,
                                                 const float* __restrict__ w1,
                                                 float* __restrict__ w40t) {
    int idx = blockIdx.x * 256 + threadIdx.x;   // 40*8192 threads
    int j = idx >> 13, k = idx & (DIN - 1);
    float v;
    if (j < 8) {
        v = gw[k * 8 + j];
    } else {
        int e = (j - 8) >> 2, h = (j - 8) & 3;
        v = w1[((size_t)e * DIN + k) * 4 + h];
    }
    w40t[idx] = v;   // coalesced write
}

// ---------------------------------------------------------------------------
// Kernel 2: decoder expert outputs outE[c][e][8] (one block per (c,e))
// ---------------------------------------------------------------------------
__device__ __forceinline__ float blk_sum256(float v, volatile float* red) {
    #pragma unroll
    for (int off = 32; off > 0; off >>= 1) v += __shfl_down(v, off, 64);
    int lane = threadIdx.x & 63, w = threadIdx.x >> 6;
    if (lane == 0) red[w] = v;
    __syncthreads();
    float s = red[0] + red[1] + red[2] + red[3];
    __syncthreads();
    return s;
}

__global__ __launch_bounds__(256) void dec_expert(
    const float* __restrict__ w1, const float* __restrict__ b1,
    const float* __restrict__ w2, const float* __restrict__ b2,
    const float* __restrict__ w3, const float* __restrict__ b3,
    const float* __restrict__ w4, const float* __restrict__ b4,
    float* __restrict__ outE) {
    __shared__ float h[HDEC];
    __shared__ float red[4];
    int c = blockIdx.x >> 3, e = blockIdx.x & 7, t = threadIdx.x;

    float a   = mishf(w1[((size_t)e * NE_ + c) * HDEC + t] + b1[e * HDEC + t]);
    float m   = blk_sum256(a, red) * (1.f / HDEC);
    float d   = a - m;
    float var = blk_sum256(d * d, red) * (1.f / HDEC);
    h[t] = d * rsqrtf(var + 1e-5f);
    __syncthreads();

    float s = b2[e * HDEC + t];
    #pragma unroll 16
    for (int i = 0; i < HDEC; ++i) s += h[i] * w2[((size_t)e * HDEC + i) * HDEC + t];
    __syncthreads();
    a   = mishf(s);
    m   = blk_sum256(a, red) * (1.f / HDEC);
    d   = a - m;
    var = blk_sum256(d * d, red) * (1.f / HDEC);
    h[t] = d * rsqrtf(var + 1e-5f);
    __syncthreads();

    s = b3[e * HDEC + t];
    #pragma unroll 16
    for (int i = 0; i < HDEC; ++i) s += h[i] * w3[((size_t)e * HDEC + i) * HDEC + t];
    __syncthreads();
    float h3 = mishf(s);

    for (int j = 0; j < 8; ++j) {
        float oj = blk_sum256(h3 * w4[((size_t)e * HDEC + t) * 8 + j], red);
        if (t == 0) outE[((size_t)c * 8 + e) * 8 + j] = oj + b4[e * 8 + j];
    }
}

// ---------------------------------------------------------------------------
// Kernel 3: LDS-staged skinny GEMM + f64 tail.
// 1024 blocks x 1024 threads (16 waves = 2 row-groups x 8 col-groups).
// w chunk (40x256) double-buffered via global_load_lds; x loads one full
// chunk deep in registers (reload-after-last-use, WAR-safe).
// ---------------------------------------------------------------------------
__global__ __launch_bounds__(1024, 4) void fused_main(
    const float* __restrict__ x,   const float* __restrict__ w40t,
    const float* __restrict__ outE,
    const float* __restrict__ gu,  const float* __restrict__ cb,
    const float* __restrict__ egb, const float* __restrict__ eb1,
    const float* __restrict__ ew2, const float* __restrict__ eb2,
    const float* __restrict__ ew3, const float* __restrict__ eb3,
    const float* __restrict__ ew4, const float* __restrict__ eb4,
    const float* __restrict__ dgw, const float* __restrict__ dgb,
    float* __restrict__ out)
{
    __shared__ float wlds[2][NCOL][CHUNK];   // 81920 B

    const int t    = threadIdx.x;
    const int lane = t & 63;
    const int wv   = t >> 6;
    const int rg   = wv >> 3;          // 0..1
    const int cg   = wv & 7;           // 0..7
    const int rowBase = blockIdx.x * ROWS_PB;
    const int j0   = cg * CPW;

    const float* __restrict__ xr0 = x + (size_t)(rowBase + rg * RPW) * DIN;

    float acc[RPW][CPW];
    #pragma unroll
    for (int r = 0; r < RPW; ++r)
        #pragma unroll
        for (int jj = 0; jj < CPW; ++jj) acc[r][jj] = 0.f;

    // ---- prologue: stage chunk 0, load x chunk 0
    stage_w(w40t, &wlds[0][0][0], t);
    float4 xa[RPW];
    #pragma unroll
    for (int r = 0; r < RPW; ++r)
        xa[r] = *(const float4*)(xr0 + (size_t)r * DIN + (lane << 2));
    __syncthreads();   // vmcnt(0) drain -> stage + xa complete

    for (int c = 0; c < NCHUNK; ++c) {
        const int cur = c & 1;
        const int cnext = c + 1;

        // stage next w-chunk into the other buffer (async, no regs)
        if (cnext < NCHUNK)
            stage_w(w40t + cnext * CHUNK, &wlds[cur ^ 1][0][0], t);

        // this wave's 5 col-fragments for its lane's 4 k values
        float4 wreg[CPW];
        #pragma unroll
        for (int jj = 0; jj < CPW; ++jj)
            wreg[jj] = *(const float4*)(&wlds[cur][j0 + jj][lane << 2]);

        #pragma unroll
        for (int r = 0; r < RPW; ++r) {
            float4 xv = xa[r];
            if (cnext < NCHUNK)   // reload same regs for next chunk (WAR-safe)
                xa[r] = *(const float4*)(xr0 + (size_t)r * DIN +
                                         cnext * CHUNK + (lane << 2));
            #pragma unroll
            for (int jj = 0; jj < CPW; ++jj) {
                float4 w = wreg[jj];
                float a0 = acc[r][jj];
                a0 = fmaf(xv.x, w.x, a0);
                a0 = fmaf(xv.y, w.y, a0);
                a0 = fmaf(xv.z, w.z, a0);
                a0 = fmaf(xv.w, w.w, a0);
                acc[r][jj] = a0;
            }
        }

        __syncthreads();   // drains vmcnt(0): stage(c+1) + xa(c+1) complete
    }

    // ---- cross-lane f64 reduction into LDS y[16][40] (aliases wlds[0])
    double* ylds = reinterpret_cast<double*>(&wlds[0][0][0]);
    #pragma unroll
    for (int r = 0; r < RPW; ++r) {
        #pragma unroll
        for (int jj = 0; jj < CPW; ++jj) {
            double v = (double)acc[r][jj];
            #pragma unroll
            for (int off = 32; off > 0; off >>= 1) v += __shfl_xor(v, off, 64);
            if (lane == 0) ylds[(rg * RPW + r) * NCOL + (j0 + jj)] = v;
        }
    }
    __syncthreads();

    // ---- per-row f64 tail: lanes 0..15 of the block, one row each
    if (t < ROWS_PB) {
        const int row = rowBase + t;
        double y[NCOL];
        #pragma unroll
        for (int j = 0; j < NCOL; ++j) y[j] = ylds[t * NCOL + j];

        // encoder gate softmax
        double gv[8], mx = -1e300, gs = 0.0;
        #pragma unroll
        for (int e = 0; e < 8; ++e) { gv[e] = y[e] + (double)egb[e]; mx = fmax(mx, gv[e]); }
        #pragma unroll
        for (int e = 0; e < 8; ++e) { gv[e] = exp(gv[e] - mx); gs += gv[e]; }
        double inv = 1.0 / gs;

        double est[4] = {0, 0, 0, 0};
        #pragma unroll
        for (int e = 0; e < 8; ++e) {
            double a[4], l1[4], p2[4], l2[4], h3[4];
            #pragma unroll
            for (int hh = 0; hh < 4; ++hh)
                a[hh] = mishd(y[8 + e * 4 + hh] + (double)eb1[e * 4 + hh]);
            ln4d(a, l1);
            #pragma unroll
            for (int hh = 0; hh < 4; ++hh) {
                double s = (double)eb2[e * 4 + hh];
                #pragma unroll
                for (int i = 0; i < 4; ++i) s += l1[i] * (double)ew2[(e * 4 + i) * 4 + hh];
                p2[hh] = mishd(s);
            }
            ln4d(p2, l2);
            #pragma unroll
            for (int hh = 0; hh < 4; ++hh) {
                double s = (double)eb3[e * 4 + hh];
                #pragma unroll
                for (int i = 0; i < 4; ++i) s += l2[i] * (double)ew3[(e * 4 + i) * 4 + hh];
                h3[hh] = mishd(s);
            }
            double g = gv[e] * inv;
            #pragma unroll
            for (int hh = 0; hh < 4; ++hh) {
                double s = (double)eb4[e * 4 + hh];
                #pragma unroll
                for (int i = 0; i < 4; ++i) s += h3[i] * (double)ew4[(e * 4 + i) * 4 + hh];
                est[hh] += g * s;
            }
        }

        // logits + gumbel + first-max argmax
        const double ulo = (double)1e-10f, uhi = (double)(1.0f - 1e-7f);
        double best = -1e300; int kb = 0;
        #pragma unroll
        for (int n = 0; n < 4; ++n) {
            double lg = 0.0;
            #pragma unroll
            for (int l = 0; l < 4; ++l) lg += est[l] * (double)cb[n * 4 + l];
            double u = (double)gu[(size_t)row * 4 + n];
            u = fmin(fmax(u, ulo), uhi);
            double z = lg - log(-log(u));   // TAU = 1
            if (z > best) { best = z; kb = n; }
        }

        // decoder gate softmax + expert combine
        double g2[8], mx2 = -1e300, gs2 = 0.0;
        #pragma unroll
        for (int e = 0; e < 8; ++e) {
            g2[e] = (double)dgw[kb * 8 + e] + (double)dgb[e];
            mx2 = fmax(mx2, g2[e]);
        }
        #pragma unroll
        for (int e = 0; e < 8; ++e) { g2[e] = exp(g2[e] - mx2); gs2 += g2[e]; }
        double inv2 = 1.0 / gs2;

        float o[8];
        #pragma unroll
        for (int j = 0; j < 8; ++j) {
            double s = 0.0;
            #pragma unroll
            for (int e = 0; e < 8; ++e)
                s += g2[e] * (double)outE[((size_t)kb * 8 + e) * 8 + j];
            o[j] = (float)(s * inv2);
        }
        float* op = out + (size_t)row * 8;
        *reinterpret_cast<float4*>(op)     = make_float4(o[0], o[1], o[2], o[3]);
        *reinterpret_cast<float4*>(op + 4) = make_float4(o[4], o[5], o[6], o[7]);
    }
}

// ---------------------------------------------------------------------------
extern "C" void kernel_launch(void* const* d_in, const int* in_sizes, int n_in,
                              void* d_out, int out_size, void* d_ws, size_t ws_size,
                              hipStream_t stream) {
    float* out = (float*)d_out;

    static const int expect[23] = {
        B_ROWS * DIN, B_ROWS * NE_, NE_ * 4,
        DIN * NEXP, NEXP,
        NEXP * DIN * 4, NEXP * 4,
        NEXP * 16, NEXP * 4,
        NEXP * 16, NEXP * 4,
        NEXP * 16, NEXP * 4,
        NE_ * NEXP, NEXP,
        NEXP * NE_ * HDEC, NEXP * HDEC,
        NEXP * HDEC * HDEC, NEXP * HDEC,
        NEXP * HDEC * HDEC, NEXP * HDEC,
        NEXP * HDEC * 8, NEXP * 8
    };
    bool ok = (n_in == 23) && (out_size == B_ROWS * 8) &&
              (ws_size >= (size_t)(DIN * NCOL + 512) * sizeof(float));
    if (ok) {
        for (int i = 0; i < 23; ++i) ok = ok && (in_sizes[i] == expect[i]);
    }
    if (!ok) {
        sentinel_k<<<(out_size + 255) / 256, 256, 0, stream>>>(out, out_size, 1.0e6f);
        return;
    }

    const float* x   = (const float*)d_in[0];
    const float* gu  = (const float*)d_in[1];
    const float* cb  = (const float*)d_in[2];
    const float* egw = (const float*)d_in[3];
    const float* egb = (const float*)d_in[4];
    const float* ew1 = (const float*)d_in[5];
    const float* eb1 = (const float*)d_in[6];
    const float* ew2 = (const float*)d_in[7];
    const float* eb2 = (const float*)d_in[8];
    const float* ew3 = (const float*)d_in[9];
    const float* eb3 = (const float*)d_in[10];
    const float* ew4 = (const float*)d_in[11];
    const float* eb4 = (const float*)d_in[12];
    const float* dgw = (const float*)d_in[13];
    const float* dgb = (const float*)d_in[14];
    const float* dw1 = (const float*)d_in[15];
    const float* db1 = (const float*)d_in[16];
    const float* dw2 = (const float*)d_in[17];
    const float* db2 = (const float*)d_in[18];
    const float* dw3 = (const float*)d_in[19];
    const float* db3 = (const float*)d_in[20];
    const float* dw4 = (const float*)d_in[21];
    const float* db4 = (const float*)d_in[22];

    float* w40t = (float*)d_ws;                     // 40*8192 floats = 1.31 MB
    float* outE = w40t + (size_t)NCOL * DIN;        // 256 floats

    prep_w40t <<<(NCOL * DIN) / 256, 256, 0, stream>>>(egw, ew1, w40t);
    dec_expert<<<NE_ * NEXP, 256, 0, stream>>>(dw1, db1, dw2, db2, dw3, db3,
                                               dw4, db4, outE);
    fused_main<<<B_ROWS / ROWS_PB, 1024, 0, stream>>>(x, w40t, outE, gu, cb,
                                                      egb, eb1, ew2, eb2, ew3,
                                                      eb3, ew4, eb4, dgw, dgb,
                                                      out);
}

// Round 6
// 507.604 us; speedup vs baseline: 2.5291x; 2.5291x over previous
//
#include <hip/hip_runtime.h>
#include <hip/hip_bf16.h>
#include <cstdint>

// Problem constants
#define B_ROWS 16384
#define DIN    8192
#define NE_    4      // codebook entries
#define NEXP   8
#define HDEC   256
#define NCOL   40     // 8 gate cols + 32 (e,lat) cols
#define CHUNK  256    // K per pipeline step (4 floats/lane)
#define NCHUNK (DIN / CHUNK)   // 32
#define RPB    8      // rows per block (= rows per wave)
#define CPW    5      // cols per wave

// ---------------- helpers ----------------
__device__ __forceinline__ float mishf(float x) {
    float sp = (x > 20.f) ? x : log1pf(expf(x));
    return x * tanhf(sp);
}
__device__ __forceinline__ double mishd(double x) {
    double sp = (x > 30.0) ? x : log1p(exp(x));
    return x * tanh(sp);
}
__device__ __forceinline__ void ln4d(const double* a, double* o) {
    double m  = (a[0] + a[1] + a[2] + a[3]) * 0.25;
    double d0 = a[0] - m, d1 = a[1] - m, d2 = a[2] - m, d3 = a[3] - m;
    double v  = (d0*d0 + d1*d1 + d2*d2 + d3*d3) * 0.25;
    double r  = 1.0 / sqrt(v + 1e-5);
    o[0] = d0*r; o[1] = d1*r; o[2] = d2*r; o[3] = d3*r;
}

// ---------------------------------------------------------------------------
// Sentinel kernel: fires only if in_sizes don't match expectations.
// ---------------------------------------------------------------------------
__global__ __launch_bounds__(256) void sentinel_k(float* __restrict__ out, int n, float v) {
    int i = blockIdx.x * 256 + threadIdx.x;
    if (i < n) out[i] = v;
}

// ---------------------------------------------------------------------------
// Kernel 1: pack TRANSPOSED w40T[j][k]
// ---------------------------------------------------------------------------
__global__ __launch_bounds__(256) void prep_w40t(const float* __restrict__ gw,
                                                 const float* __restrict__ w1,
                                                 float* __restrict__ w40t) {
    int idx = blockIdx.x * 256 + threadIdx.x;   // 40*8192 threads
    int j = idx >> 13, k = idx & (DIN - 1);
    float v;
    if (j < 8) {
        v = gw[k * 8 + j];
    } else {
        int e = (j - 8) >> 2, h = (j - 8) & 3;
        v = w1[((size_t)e * DIN + k) * 4 + h];
    }
    w40t[idx] = v;   // coalesced write
}

// ---------------------------------------------------------------------------
// Kernel 2: decoder expert outputs outE[c][e][8] (one block per (c,e))
// ---------------------------------------------------------------------------
__device__ __forceinline__ float blk_sum256(float v, volatile float* red) {
    #pragma unroll
    for (int off = 32; off > 0; off >>= 1) v += __shfl_down(v, off, 64);
    int lane = threadIdx.x & 63, w = threadIdx.x >> 6;
    if (lane == 0) red[w] = v;
    __syncthreads();
    float s = red[0] + red[1] + red[2] + red[3];
    __syncthreads();
    return s;
}

__global__ __launch_bounds__(256) void dec_expert(
    const float* __restrict__ w1, const float* __restrict__ b1,
    const float* __restrict__ w2, const float* __restrict__ b2,
    const float* __restrict__ w3, const float* __restrict__ b3,
    const float* __restrict__ w4, const float* __restrict__ b4,
    float* __restrict__ outE) {
    __shared__ float h[HDEC];
    __shared__ float red[4];
    int c = blockIdx.x >> 3, e = blockIdx.x & 7, t = threadIdx.x;

    float a   = mishf(w1[((size_t)e * NE_ + c) * HDEC + t] + b1[e * HDEC + t]);
    float m   = blk_sum256(a, red) * (1.f / HDEC);
    float d   = a - m;
    float var = blk_sum256(d * d, red) * (1.f / HDEC);
    h[t] = d * rsqrtf(var + 1e-5f);
    __syncthreads();

    float s = b2[e * HDEC + t];
    #pragma unroll 16
    for (int i = 0; i < HDEC; ++i) s += h[i] * w2[((size_t)e * HDEC + i) * HDEC + t];
    __syncthreads();
    a   = mishf(s);
    m   = blk_sum256(a, red) * (1.f / HDEC);
    d   = a - m;
    var = blk_sum256(d * d, red) * (1.f / HDEC);
    h[t] = d * rsqrtf(var + 1e-5f);
    __syncthreads();

    s = b3[e * HDEC + t];
    #pragma unroll 16
    for (int i = 0; i < HDEC; ++i) s += h[i] * w3[((size_t)e * HDEC + i) * HDEC + t];
    __syncthreads();
    float h3 = mishf(s);

    for (int j = 0; j < 8; ++j) {
        float oj = blk_sum256(h3 * w4[((size_t)e * HDEC + t) * 8 + j], red);
        if (t == 0) outE[((size_t)c * 8 + e) * 8 + j] = oj + b4[e * 8 + j];
    }
}

// ---------------------------------------------------------------------------
// Kernel 3: barrier-free skinny GEMM. 2048 blocks x 512 threads (8 waves).
// Block = 8 rows; wave cg handles cols [cg*5, +5), full K.
// x: 8 rows all in flight (xa rotation); w: 5 float4/chunk from L2.
// Writes y[row][40] f64 to workspace.
// ---------------------------------------------------------------------------
__global__ __launch_bounds__(512, 2) void gemm_main(
    const float* __restrict__ x, const float* __restrict__ w40t,
    double* __restrict__ y)
{
    const int t    = threadIdx.x;
    const int lane = t & 63;
    const int cg   = t >> 6;           // 0..7
    const int rowBase = blockIdx.x * RPB;
    const int j0   = cg * CPW;

    const float* __restrict__ xr = x + (size_t)rowBase * DIN + (lane << 2);
    const float* __restrict__ wr = w40t + (size_t)j0 * DIN + (lane << 2);

    float acc[RPB][CPW];
    #pragma unroll
    for (int r = 0; r < RPB; ++r)
        #pragma unroll
        for (int jj = 0; jj < CPW; ++jj) acc[r][jj] = 0.f;

    // prologue: all 8 rows' chunk-0 x in flight
    float4 xa[RPB];
    #pragma unroll
    for (int r = 0; r < RPB; ++r)
        xa[r] = *(const float4*)(xr + (size_t)r * DIN);

    for (int c = 0; c < NCHUNK; ++c) {
        float4 wv[CPW];
        #pragma unroll
        for (int jj = 0; jj < CPW; ++jj)
            wv[jj] = *(const float4*)(wr + (size_t)jj * DIN + c * CHUNK);

        const int koff = (c + 1) * CHUNK;
        #pragma unroll
        for (int r = 0; r < RPB; ++r) {
            float4 xv = xa[r];
            if (c + 1 < NCHUNK)   // reload same reg slot (issue-after-use, WAR-safe)
                xa[r] = *(const float4*)(xr + (size_t)r * DIN + koff);
            #pragma unroll
            for (int jj = 0; jj < CPW; ++jj) {
                float a0 = acc[r][jj];
                a0 = fmaf(xv.x, wv[jj].x, a0);
                a0 = fmaf(xv.y, wv[jj].y, a0);
                a0 = fmaf(xv.z, wv[jj].z, a0);
                a0 = fmaf(xv.w, wv[jj].w, a0);
                acc[r][jj] = a0;
            }
        }
    }

    // f64 cross-lane reduction (same lane/k partition as R4/R5, verified)
    #pragma unroll
    for (int r = 0; r < RPB; ++r) {
        #pragma unroll
        for (int jj = 0; jj < CPW; ++jj) {
            double v = (double)acc[r][jj];
            #pragma unroll
            for (int off = 32; off > 0; off >>= 1) v += __shfl_xor(v, off, 64);
            if (lane == 0) y[(size_t)(rowBase + r) * NCOL + (j0 + jj)] = v;
        }
    }
}

// ---------------------------------------------------------------------------
// Kernel 4: per-row f64 tail (verified math from R4/R5). 1 thread = 1 row.
// ---------------------------------------------------------------------------
__global__ __launch_bounds__(64) void tail_k(
    const double* __restrict__ yg, const float* __restrict__ outE,
    const float* __restrict__ gu,  const float* __restrict__ cb,
    const float* __restrict__ egb, const float* __restrict__ eb1,
    const float* __restrict__ ew2, const float* __restrict__ eb2,
    const float* __restrict__ ew3, const float* __restrict__ eb3,
    const float* __restrict__ ew4, const float* __restrict__ eb4,
    const float* __restrict__ dgw, const float* __restrict__ dgb,
    float* __restrict__ out)
{
    const int row = blockIdx.x * 64 + threadIdx.x;
    const double* __restrict__ y = yg + (size_t)row * NCOL;

    // encoder gate softmax
    double gv[8], mx = -1e300, gs = 0.0;
    #pragma unroll
    for (int e = 0; e < 8; ++e) { gv[e] = y[e] + (double)egb[e]; mx = fmax(mx, gv[e]); }
    #pragma unroll
    for (int e = 0; e < 8; ++e) { gv[e] = exp(gv[e] - mx); gs += gv[e]; }
    double inv = 1.0 / gs;

    double est[4] = {0, 0, 0, 0};
    #pragma unroll
    for (int e = 0; e < 8; ++e) {
        double a[4], l1[4], p2[4], l2[4], h3[4];
        #pragma unroll
        for (int hh = 0; hh < 4; ++hh)
            a[hh] = mishd(y[8 + e * 4 + hh] + (double)eb1[e * 4 + hh]);
        ln4d(a, l1);
        #pragma unroll
        for (int hh = 0; hh < 4; ++hh) {
            double s = (double)eb2[e * 4 + hh];
            #pragma unroll
            for (int i = 0; i < 4; ++i) s += l1[i] * (double)ew2[(e * 4 + i) * 4 + hh];
            p2[hh] = mishd(s);
        }
        ln4d(p2, l2);
        #pragma unroll
        for (int hh = 0; hh < 4; ++hh) {
            double s = (double)eb3[e * 4 + hh];
            #pragma unroll
            for (int i = 0; i < 4; ++i) s += l2[i] * (double)ew3[(e * 4 + i) * 4 + hh];
            h3[hh] = mishd(s);
        }
        double g = gv[e] * inv;
        #pragma unroll
        for (int hh = 0; hh < 4; ++hh) {
            double s = (double)eb4[e * 4 + hh];
            #pragma unroll
            for (int i = 0; i < 4; ++i) s += h3[i] * (double)ew4[(e * 4 + i) * 4 + hh];
            est[hh] += g * s;
        }
    }

    // logits + gumbel + first-max argmax
    const double ulo = (double)1e-10f, uhi = (double)(1.0f - 1e-7f);
    double best = -1e300; int kb = 0;
    #pragma unroll
    for (int n = 0; n < 4; ++n) {
        double lg = 0.0;
        #pragma unroll
        for (int l = 0; l < 4; ++l) lg += est[l] * (double)cb[n * 4 + l];
        double u = (double)gu[(size_t)row * 4 + n];
        u = fmin(fmax(u, ulo), uhi);
        double z = lg - log(-log(u));   // TAU = 1
        if (z > best) { best = z; kb = n; }
    }

    // decoder gate softmax + expert combine
    double g2[8], mx2 = -1e300, gs2 = 0.0;
    #pragma unroll
    for (int e = 0; e < 8; ++e) {
        g2[e] = (double)dgw[kb * 8 + e] + (double)dgb[e];
        mx2 = fmax(mx2, g2[e]);
    }
    #pragma unroll
    for (int e = 0; e < 8; ++e) { g2[e] = exp(g2[e] - mx2); gs2 += g2[e]; }
    double inv2 = 1.0 / gs2;

    float o[8];
    #pragma unroll
    for (int j = 0; j < 8; ++j) {
        double s = 0.0;
        #pragma unroll
        for (int e = 0; e < 8; ++e)
            s += g2[e] * (double)outE[((size_t)kb * 8 + e) * 8 + j];
        o[j] = (float)(s * inv2);
    }
    float* op = out + (size_t)row * 8;
    *reinterpret_cast<float4*>(op)     = make_float4(o[0], o[1], o[2], o[3]);
    *reinterpret_cast<float4*>(op + 4) = make_float4(o[4], o[5], o[6], o[7]);
}

// ---------------------------------------------------------------------------
extern "C" void kernel_launch(void* const* d_in, const int* in_sizes, int n_in,
                              void* d_out, int out_size, void* d_ws, size_t ws_size,
                              hipStream_t stream) {
    float* out = (float*)d_out;

    static const int expect[23] = {
        B_ROWS * DIN, B_ROWS * NE_, NE_ * 4,
        DIN * NEXP, NEXP,
        NEXP * DIN * 4, NEXP * 4,
        NEXP * 16, NEXP * 4,
        NEXP * 16, NEXP * 4,
        NEXP * 16, NEXP * 4,
        NE_ * NEXP, NEXP,
        NEXP * NE_ * HDEC, NEXP * HDEC,
        NEXP * HDEC * HDEC, NEXP * HDEC,
        NEXP * HDEC * HDEC, NEXP * HDEC,
        NEXP * HDEC * 8, NEXP * 8
    };
    // ws layout: w40t (1.31 MB f32) | outE (256 f32 + pad) | y (16384*40 f64 = 5.24 MB)
    const size_t need = (size_t)(NCOL * DIN + 512) * sizeof(float)
                      + (size_t)B_ROWS * NCOL * sizeof(double);
    bool ok = (n_in == 23) && (out_size == B_ROWS * 8) && (ws_size >= need);
    if (ok) {
        for (int i = 0; i < 23; ++i) ok = ok && (in_sizes[i] == expect[i]);
    }
    if (!ok) {
        sentinel_k<<<(out_size + 255) / 256, 256, 0, stream>>>(out, out_size, 1.0e6f);
        return;
    }

    const float* x   = (const float*)d_in[0];
    const float* gu  = (const float*)d_in[1];
    const float* cb  = (const float*)d_in[2];
    const float* egw = (const float*)d_in[3];
    const float* egb = (const float*)d_in[4];
    const float* ew1 = (const float*)d_in[5];
    const float* eb1 = (const float*)d_in[6];
    const float* ew2 = (const float*)d_in[7];
    const float* eb2 = (const float*)d_in[8];
    const float* ew3 = (const float*)d_in[9];
    const float* eb3 = (const float*)d_in[10];
    const float* ew4 = (const float*)d_in[11];
    const float* eb4 = (const float*)d_in[12];
    const float* dgw = (const float*)d_in[13];
    const float* dgb = (const float*)d_in[14];
    const float* dw1 = (const float*)d_in[15];
    const float* db1 = (const float*)d_in[16];
    const float* dw2 = (const float*)d_in[17];
    const float* db2 = (const float*)d_in[18];
    const float* dw3 = (const float*)d_in[19];
    const float* db3 = (const float*)d_in[20];
    const float* dw4 = (const float*)d_in[21];
    const float* db4 = (const float*)d_in[22];

    float*  w40t = (float*)d_ws;                      // 40*8192 f32
    float*  outE = w40t + (size_t)NCOL * DIN;         // 256 f32 (+pad to 512)
    double* yws  = (double*)(w40t + (size_t)NCOL * DIN + 512);

    prep_w40t <<<(NCOL * DIN) / 256, 256, 0, stream>>>(egw, ew1, w40t);
    dec_expert<<<NE_ * NEXP, 256, 0, stream>>>(dw1, db1, dw2, db2, dw3, db3,
                                               dw4, db4, outE);
    gemm_main <<<B_ROWS / RPB, 512, 0, stream>>>(x, w40t, yws);
    tail_k    <<<B_ROWS / 64, 64, 0, stream>>>(yws, outE, gu, cb, egb, eb1,
                                               ew2, eb2, ew3, eb3, ew4, eb4,
                                               dgw, dgb, out);
}